// Round 5
// baseline (463.633 us; speedup 1.0000x reference)
//
#include <hip/hip_runtime.h>

// PointNetKnnInterpolator on MI355X (gfx950).
// R15: CLEAN occupancy test. R14 failed because __launch_bounds__(512,6) with
// the 2-tile core (64 acc regs) forced a ~64-85 reg cap -> total spill
// (VGPR 40, WRITE 12.5MB->611MB, 1.2GB scratch traffic, 403us). This round:
// 1 tile/iter (peak live ~44 regs + addressing), launch_bounds(512,6),
// grid 768 = 3 blocks/CU (LDS 48.5KB allows exactly 3; 4 would need <=40KB
// which 42KB of distinct weights forbids). 6 waves/SIMD vs R12's 4.
// Gate counters: WRITE_SIZE ~12.5MB & VGPR ~48-72 = no spill; Occupancy ~50.
// Verified pieces kept: R12 stage order (mm3 on raw h first, relu in place),
// k67 bias hooks (b0a/b1a), b0b acc-init, b1b post-max, reg-only shfl_xor
// epilogue (bank conflicts = 0), atomic work-stealing tail.
// Falsified so far: MFMA count (R11), gather prefetch (R11), LDS frag BW
// (R12), per-wave ILP (R12), precompute-gather (R13), spill-occupancy (R14).

typedef _Float16 f16x8 __attribute__((ext_vector_type(8)));
typedef _Float16 f16x4 __attribute__((ext_vector_type(4)));
typedef float    f32x4 __attribute__((ext_vector_type(4)));

constexpr int NX     = 20000;
constexpr int NROWS  = 50000 * 8;    // NY * K
constexpr int NTILES = NROWS / 16;   // 25000
constexpr int NFRAG  = 48;           // W0a 12 | Wsa 12 | W1a 8 | W0b 8 | W1b 8
constexpr int BW     = 8;            // waves per block
constexpr int BLOCK  = 64 * BW;      // 512
constexpr int GRID   = 768;          // 3 blocks/CU

// d_ws layout: x16[NX*64] (f16) | steal counter (unsigned)
#define CTR_BYTE_OFF ((size_t)NX * 64 * 2)

__global__ void prep_x(const float* __restrict__ x, char* __restrict__ ws) {
    _Float16* x16 = (_Float16*)ws;
    const int i = blockIdx.x * blockDim.x + threadIdx.x;   // one float4 each
    if (i < NX * 16) {
        float4 v = ((const float4*)x)[i];
        f16x4 o = {(_Float16)v.x, (_Float16)v.y, (_Float16)v.z, (_Float16)v.w};
        *(f16x4*)(x16 + (size_t)i * 4) = o;
    }
    if (blockIdx.x == 0 && threadIdx.x == 0)
        *(unsigned*)(ws + CTR_BYTE_OFF) = 0u;
}

// relu + repack accumulator (C-layout) into the two K=64 B-fragments.
// frag s element j  <->  acc[t=2s+(j>>2)][r=j&3]   (matches PHI weight layout)
static __device__ __forceinline__ void pack_relu(const f32x4* A, f16x8* bf) {
#pragma unroll
    for (int s = 0; s < 2; ++s) {
        f16x8 r;
#pragma unroll
        for (int e = 0; e < 8; ++e) {
            float v = A[2 * s + (e >> 2)][e & 3];
            r[e] = (_Float16)(v > 0.0f ? v : 0.0f);
        }
        bf[s] = r;
    }
}

__global__ __launch_bounds__(BLOCK, 6)
void pointnet_fused(char* __restrict__ ws,
                    const float* __restrict__ pos_x,
                    const float* __restrict__ pos_y,
                    const int*   __restrict__ x_idx,
                    const float* __restrict__ W0a, const float* __restrict__ b0a,
                    const float* __restrict__ W1a, const float* __restrict__ b1a,
                    const float* __restrict__ Wsa,
                    const float* __restrict__ W0b, const float* __restrict__ b0b,
                    const float* __restrict__ W1b, const float* __restrict__ b1b,
                    float* __restrict__ out)
{
    __shared__ __align__(16) _Float16 bfrag[NFRAG * 64 * 8];   // 48 KiB
    __shared__ __align__(16) float    bias3f[64];              // b0b (mm4 acc init)
    __shared__ __align__(16) float    bias5f[64];              // b1b (post-max add)

    const _Float16* x16 = (const _Float16*)ws;
    unsigned* ctr = (unsigned*)(ws + CTR_BYTE_OFF);

    const int tid = threadIdx.x;

    // ---- fill weight fragments (A operands, transposed; PHI-permuted K) ----
    // grp0 W0a(identity,+b0a@k67)  grp1 Wsa(identity,+b1a@k67)
    // grp2 W1a(PHI) grp3 W0b(PHI) grp4 W1b(PHI)
    for (int p = tid; p < NFRAG * 64; p += BLOCK) {
        const int f = p >> 6, l = p & 63;
        const int q = l >> 4, n0 = l & 15;
        int grp, fl;
        if      (f < 12) { grp = 0; fl = f; }
        else if (f < 24) { grp = 1; fl = f - 12; }
        else if (f < 32) { grp = 2; fl = f - 24; }
        else if (f < 40) { grp = 3; fl = f - 32; }
        else             { grp = 4; fl = f - 40; }
        const int s = fl >> 2, t = fl & 3;
        const int col = t * 16 + n0;
        f16x8 v;
#pragma unroll
        for (int j = 0; j < 8; ++j) {
            const int k = 32 * s + 8 * q + j;
            float val = 0.0f;
            if      (grp == 0) val = (k < 67) ? W0a[k * 64 + col] : (k == 67 ? b0a[col] : 0.0f);
            else if (grp == 1) val = (k < 67) ? Wsa[k * 64 + col] : (k == 67 ? b1a[col] : 0.0f);
            else {
                const float* W = (grp == 2) ? W1a : (grp == 3) ? W0b : W1b;
                const int row = 32 * s + 16 * (j >> 2) + 4 * q + (j & 3);  // PHI(k), s<2
                val = W[row * 64 + col];
            }
            v[j] = (_Float16)val;
        }
        *(f16x8*)&bfrag[p * 8] = v;
    }
    if (tid < 64)       bias3f[tid]      = b0b[tid];
    else if (tid < 128) bias5f[tid - 64] = b1b[tid - 64];
    __syncthreads();

    const int lane = tid & 63;
    const int wv   = tid >> 6;
    const int n0   = lane & 15;   // B col = data row (dr) / C-layout col
    const int q    = lane >> 4;

    const unsigned gwave  = blockIdx.x * BW + wv;
    const unsigned nwaves = GRID * BW;   // 6144

#define WFRAG(fid) (*(const f16x8*)&bfrag[(((fid) * 64) + lane) * 8])

    unsigned pcur = gwave;                    // round 1 static (no herd)
    while (pcur < NTILES) {
        unsigned pnxt = 0;
        if (lane == 0) pnxt = nwaves + atomicAdd(ctr, 1u);   // steal next tile

        const int tile = (int)pcur;

        // ---- gather h: lane(n0,q) = h[dr=n0][feats 32s+8q+j] ----
        f16x8 h0, h1, h2;
        {
            const int row = tile * 16 + n0;
            const int xi  = x_idx[row];
            const _Float16* xp = x16 + (long)xi * 64 + q * 8;
            h0 = *(const f16x8*)(xp);
            h1 = *(const f16x8*)(xp + 32);
            f16x8 z = {};
            h2 = z;
            if (q == 0) {                      // k=64..66 diff, k=67 = 1.0 (bias hook)
                const int yi = row >> 3;
#pragma unroll
                for (int j = 0; j < 3; ++j)
                    h2[j] = (_Float16)(pos_x[xi * 3 + j] - pos_y[yi * 3 + j]);
                h2[3] = (_Float16)1.0f;
            }
        }

        // ---- mm3 on raw h: A2 = (h @ Wsa)^T + b1a (k67 hook) ----
        f32x4 A2[4];
#pragma unroll
        for (int t = 0; t < 4; ++t) A2[t] = (f32x4){0.f, 0.f, 0.f, 0.f};
#pragma unroll
        for (int t = 0; t < 4; ++t) A2[t] = __builtin_amdgcn_mfma_f32_16x16x32_f16(WFRAG(12 + t), h0, A2[t], 0, 0, 0);
#pragma unroll
        for (int t = 0; t < 4; ++t) A2[t] = __builtin_amdgcn_mfma_f32_16x16x32_f16(WFRAG(16 + t), h1, A2[t], 0, 0, 0);
#pragma unroll
        for (int t = 0; t < 4; ++t) A2[t] = __builtin_amdgcn_mfma_f32_16x16x32_f16(WFRAG(20 + t), h2, A2[t], 0, 0, 0);

        // ---- relu h in place (pad 1.0 survives) ----
#pragma unroll
        for (int j = 0; j < 8; ++j) {
            h0[j] = h0[j] > (_Float16)0 ? h0[j] : (_Float16)0;
            h1[j] = h1[j] > (_Float16)0 ? h1[j] : (_Float16)0;
            h2[j] = h2[j] > (_Float16)0 ? h2[j] : (_Float16)0;
        }

        // ---- mm1: A1 = (relu(h) @ W0a)^T + b0a (k67 hook) ----
        f32x4 A1[4];
#pragma unroll
        for (int t = 0; t < 4; ++t) A1[t] = (f32x4){0.f, 0.f, 0.f, 0.f};
#pragma unroll
        for (int t = 0; t < 4; ++t) A1[t] = __builtin_amdgcn_mfma_f32_16x16x32_f16(WFRAG(0 + t), h0, A1[t], 0, 0, 0);
#pragma unroll
        for (int t = 0; t < 4; ++t) A1[t] = __builtin_amdgcn_mfma_f32_16x16x32_f16(WFRAG(4 + t), h1, A1[t], 0, 0, 0);
#pragma unroll
        for (int t = 0; t < 4; ++t) A1[t] = __builtin_amdgcn_mfma_f32_16x16x32_f16(WFRAG(8 + t), h2, A1[t], 0, 0, 0);

        // ---- mm2: A2 += (relu(net) @ W1a)^T ----
        f16x8 bf[2];
        pack_relu(A1, bf);
#pragma unroll
        for (int s = 0; s < 2; ++s)
#pragma unroll
            for (int t = 0; t < 4; ++t)
                A2[t] = __builtin_amdgcn_mfma_f32_16x16x32_f16(WFRAG(24 + s * 4 + t), bf[s], A2[t], 0, 0, 0);

        // ---- mm4: A3 = b0b (broadcast LDS init) + (relu(h2) @ W0b)^T ----
        pack_relu(A2, bf);
        f32x4 A3[4];
#pragma unroll
        for (int t = 0; t < 4; ++t) A3[t] = *(const f32x4*)&bias3f[16 * t + 4 * q];
#pragma unroll
        for (int s = 0; s < 2; ++s)
#pragma unroll
            for (int t = 0; t < 4; ++t)
                A3[t] = __builtin_amdgcn_mfma_f32_16x16x32_f16(WFRAG(32 + s * 4 + t), bf[s], A3[t], 0, 0, 0);

        // ---- mm5: A2 += (relu(net2) @ W1b)^T  -> h3^T (b1b deferred past max) ----
        pack_relu(A3, bf);
#pragma unroll
        for (int s = 0; s < 2; ++s)
#pragma unroll
            for (int t = 0; t < 4; ++t)
                A2[t] = __builtin_amdgcn_mfma_f32_16x16x32_f16(WFRAG(40 + s * 4 + t), bf[s], A2[t], 0, 0, 0);

        // ---- epilogue: in-register f16 max over dr (lane bits 0..2), no LDS ----
        {
            union U { f16x8 h; int i[4]; };
            U pa, pb;
#pragma unroll
            for (int e = 0; e < 8; ++e) {
                pa.h[e] = (_Float16)A2[(e >> 2)][e & 3];       // feats t=0,1
                pb.h[e] = (_Float16)A2[2 + (e >> 2)][e & 3];   // feats t=2,3
            }
#pragma unroll
            for (int st = 0; st < 3; ++st) {
                const int m = 1 << st;                         // xor 1,2,4
                U qa, qb;
#pragma unroll
                for (int d = 0; d < 4; ++d) {
                    qa.i[d] = __shfl_xor(pa.i[d], m, 64);
                    qb.i[d] = __shfl_xor(pb.i[d], m, 64);
                }
#pragma unroll
                for (int e = 0; e < 8; ++e) {
                    pa.h[e] = pa.h[e] > qa.h[e] ? pa.h[e] : qa.h[e];
                    pb.h[e] = pb.h[e] > qb.h[e] ? pb.h[e] : qb.h[e];
                }
            }
            if ((n0 & 7) == 0) {
                const int y = tile * 2 + (n0 >> 3);
                float* op = out + (long)y * 64;
#pragma unroll
                for (int t = 0; t < 4; ++t) {
                    const f32x4 bb = *(const f32x4*)&bias5f[16 * t + 4 * q];
                    const int e0 = (t & 1) * 4;
                    float4 vst;
                    if (t < 2) vst = {(float)pa.h[e0 + 0] + bb[0], (float)pa.h[e0 + 1] + bb[1],
                                      (float)pa.h[e0 + 2] + bb[2], (float)pa.h[e0 + 3] + bb[3]};
                    else       vst = {(float)pb.h[e0 + 0] + bb[0], (float)pb.h[e0 + 1] + bb[1],
                                      (float)pb.h[e0 + 2] + bb[2], (float)pb.h[e0 + 3] + bb[3]};
                    *(float4*)(op + 16 * t + 4 * q) = vst;
                }
            }
        }

        pnxt = (unsigned)__shfl((int)pnxt, 0);   // late use: atomic latency hidden
        pcur = pnxt;
    }
#undef WFRAG
}

extern "C" void kernel_launch(void* const* d_in, const int* in_sizes, int n_in,
                              void* d_out, int out_size, void* d_ws, size_t ws_size,
                              hipStream_t stream) {
    (void)in_sizes; (void)n_in; (void)ws_size; (void)out_size;
    char* ws = (char*)d_ws;

    prep_x<<<(NX * 16 + 255) / 256, 256, 0, stream>>>((const float*)d_in[0], ws);

    pointnet_fused<<<GRID, BLOCK, 0, stream>>>(
        ws,
        (const float*)d_in[1],   // pos_x
        (const float*)d_in[2],   // pos_y
        (const int*)  d_in[3],   // x_idx
        (const float*)d_in[5],  (const float*)d_in[6],   // W0a, b0a
        (const float*)d_in[7],  (const float*)d_in[8],   // W1a, b1a
        (const float*)d_in[9],                            // Wsa
        (const float*)d_in[10], (const float*)d_in[11],  // W0b, b0b
        (const float*)d_in[12], (const float*)d_in[13],  // W1b, b1b
        (float*)d_out);
}

// Round 6
// 328.088 us; speedup vs baseline: 1.4131x; 1.4131x over previous
//
#include <hip/hip_runtime.h>

// PointNetKnnInterpolator on MI355X (gfx950).
// R16: R14 body at the known-good launch config (512,4)+grid512.
// R14/R15 post-mortem: __launch_bounds__(512,6) makes the compiler split the
// 80-reg budget ~40 VGPR + ~40 AGPR -> non-acc state spills to scratch
// (WRITE 12.5MB -> 300-611MB, wall = scratch BW). Lever closed.
// What survives: R10-R12 ran at ~31% occupancy = reg-limited 3 waves/SIMD
// (R12 footprint: 56 VGPR + 96 acc = 152 -> floor(512/152)=3). This body
// eliminates A3 (mm4 accumulates into the A1 slots) -> 64 acc + ~56 VGPR
// = ~120 <= 128 -> 4 waves/SIMD at (512,4) with no structural change.
// Plus the two verified-but-unmeasured-on-fast-base wins:
//   - reg-only shfl_xor(1/2/4) f16 max epilogue: bank conflicts 600k -> 0,
//     both threadfences gone, ebuf (18KB LDS) gone.
//   - atomic work-stealing: kills the 3.05-pairs/wave static tail.
// Falsified: MFMA count (R11), gather prefetch (R11), LDS frag BW (R12),
// pair-ILP (R12), precompute-gather (R13), launch_bounds>=6 (R14/R15).
// Gate counters this round: WRITE ~12.5MB & VGPR ~56-64 (no spill);
// occupancy 31 -> ~40-44. Then fused 44.4 -> 34-39 us if latency-bound.

typedef _Float16 f16x8 __attribute__((ext_vector_type(8)));
typedef _Float16 f16x4 __attribute__((ext_vector_type(4)));
typedef float    f32x4 __attribute__((ext_vector_type(4)));

constexpr int NX     = 20000;
constexpr int NROWS  = 50000 * 8;    // NY * K
constexpr int NTILES = NROWS / 16;   // 25000
constexpr int NPAIRS = NTILES / 2;   // 12500
constexpr int NFRAG  = 48;           // W0a 12 | Wsa 12 | W1a 8 | W0b 8 | W1b 8
constexpr int BW     = 8;            // waves per block
constexpr int BLOCK  = 64 * BW;      // 512
constexpr int GRID   = 512;

// d_ws layout: x16[NX*64] (f16) | steal counter (unsigned)
#define CTR_BYTE_OFF ((size_t)NX * 64 * 2)

__global__ void prep_x(const float* __restrict__ x, char* __restrict__ ws) {
    _Float16* x16 = (_Float16*)ws;
    const int i = blockIdx.x * blockDim.x + threadIdx.x;   // one float4 each
    if (i < NX * 16) {
        float4 v = ((const float4*)x)[i];
        f16x4 o = {(_Float16)v.x, (_Float16)v.y, (_Float16)v.z, (_Float16)v.w};
        *(f16x4*)(x16 + (size_t)i * 4) = o;
    }
    if (blockIdx.x == 0 && threadIdx.x == 0)
        *(unsigned*)(ws + CTR_BYTE_OFF) = 0u;
}

// relu + repack accumulator (C-layout) into the two K=64 B-fragments.
// frag s element j  <->  acc[t=2s+(j>>2)][r=j&3]   (matches PHI weight layout)
static __device__ __forceinline__ void pack_relu(const f32x4* A, f16x8* bf) {
#pragma unroll
    for (int s = 0; s < 2; ++s) {
        f16x8 r;
#pragma unroll
        for (int e = 0; e < 8; ++e) {
            float v = A[2 * s + (e >> 2)][e & 3];
            r[e] = (_Float16)(v > 0.0f ? v : 0.0f);
        }
        bf[s] = r;
    }
}

__global__ __launch_bounds__(BLOCK, 4)
void pointnet_fused(char* __restrict__ ws,
                    const float* __restrict__ pos_x,
                    const float* __restrict__ pos_y,
                    const int*   __restrict__ x_idx,
                    const float* __restrict__ W0a, const float* __restrict__ b0a,
                    const float* __restrict__ W1a, const float* __restrict__ b1a,
                    const float* __restrict__ Wsa,
                    const float* __restrict__ W0b, const float* __restrict__ b0b,
                    const float* __restrict__ W1b, const float* __restrict__ b1b,
                    float* __restrict__ out)
{
    __shared__ __align__(16) _Float16 bfrag[NFRAG * 64 * 8];   // 48 KiB
    __shared__ __align__(16) float    bias3f[64];              // b0b (mm4 acc init)
    __shared__ __align__(16) float    bias5f[64];              // b1b (post-max add)

    const _Float16* x16 = (const _Float16*)ws;
    unsigned* ctr = (unsigned*)(ws + CTR_BYTE_OFF);

    const int tid = threadIdx.x;

    // ---- fill weight fragments (A operands, transposed; PHI-permuted K) ----
    // grp0 W0a(identity,+b0a@k67)  grp1 Wsa(identity,+b1a@k67)
    // grp2 W1a(PHI) grp3 W0b(PHI) grp4 W1b(PHI)
    for (int p = tid; p < NFRAG * 64; p += BLOCK) {
        const int f = p >> 6, l = p & 63;
        const int q = l >> 4, n0 = l & 15;
        int grp, fl;
        if      (f < 12) { grp = 0; fl = f; }
        else if (f < 24) { grp = 1; fl = f - 12; }
        else if (f < 32) { grp = 2; fl = f - 24; }
        else if (f < 40) { grp = 3; fl = f - 32; }
        else             { grp = 4; fl = f - 40; }
        const int s = fl >> 2, t = fl & 3;
        const int col = t * 16 + n0;
        f16x8 v;
#pragma unroll
        for (int j = 0; j < 8; ++j) {
            const int k = 32 * s + 8 * q + j;
            float val = 0.0f;
            if      (grp == 0) val = (k < 67) ? W0a[k * 64 + col] : (k == 67 ? b0a[col] : 0.0f);
            else if (grp == 1) val = (k < 67) ? Wsa[k * 64 + col] : (k == 67 ? b1a[col] : 0.0f);
            else {
                const float* W = (grp == 2) ? W1a : (grp == 3) ? W0b : W1b;
                const int row = 32 * s + 16 * (j >> 2) + 4 * q + (j & 3);  // PHI(k), s<2
                val = W[row * 64 + col];
            }
            v[j] = (_Float16)val;
        }
        *(f16x8*)&bfrag[p * 8] = v;
    }
    if (tid < 64)       bias3f[tid]      = b0b[tid];
    else if (tid < 128) bias5f[tid - 64] = b1b[tid - 64];
    __syncthreads();

    const int lane = tid & 63;
    const int wv   = tid >> 6;
    const int n0   = lane & 15;   // B col = data row (dr) / C-layout col
    const int q    = lane >> 4;

    const unsigned gwave  = blockIdx.x * BW + wv;
    const unsigned nwaves = GRID * BW;   // 4096

#define WFRAG(fid) (*(const f16x8*)&bfrag[(((fid) * 64) + lane) * 8])

    unsigned pcur = gwave;                    // round 1 static (no herd)
    while (pcur < NPAIRS) {
        unsigned pnxt = 0;
        if (lane == 0) pnxt = nwaves + atomicAdd(ctr, 1u);   // steal next pair

        const int tA = (int)pcur * 2;

        // ---- gather both tiles' h (independent -> latencies overlap) ----
        f16x8 h[2][3];
#pragma unroll
        for (int u = 0; u < 2; ++u) {
            const int row = (tA + u) * 16 + n0;
            const int xi  = x_idx[row];
            const _Float16* xp = x16 + (long)xi * 64 + q * 8;
            h[u][0] = *(const f16x8*)(xp);
            h[u][1] = *(const f16x8*)(xp + 32);
            f16x8 z = {};
            h[u][2] = z;
            if (q == 0) {                      // k=64..66 diff, k=67 = 1.0 (bias hook)
                const int yi = row >> 3;
#pragma unroll
                for (int j = 0; j < 3; ++j)
                    h[u][2][j] = (_Float16)(pos_x[xi * 3 + j] - pos_y[yi * 3 + j]);
                h[u][2][3] = (_Float16)1.0f;
            }
        }

        // ---- mm3 on raw h: A2 = (h @ Wsa)^T + b1a (k67 hook) ----
        f32x4 A2[2][4];
#pragma unroll
        for (int u = 0; u < 2; ++u)
#pragma unroll
            for (int t = 0; t < 4; ++t) A2[u][t] = (f32x4){0.f, 0.f, 0.f, 0.f};
#pragma unroll
        for (int s = 0; s < 3; ++s)
#pragma unroll
            for (int t = 0; t < 4; ++t) {
                const f16x8 w = WFRAG(12 + s * 4 + t);     // one LDS read, two MFMAs
                A2[0][t] = __builtin_amdgcn_mfma_f32_16x16x32_f16(w, h[0][s], A2[0][t], 0, 0, 0);
                A2[1][t] = __builtin_amdgcn_mfma_f32_16x16x32_f16(w, h[1][s], A2[1][t], 0, 0, 0);
            }

        // ---- relu h in place (pad 1.0 survives) ----
#pragma unroll
        for (int u = 0; u < 2; ++u)
#pragma unroll
            for (int s = 0; s < 3; ++s)
#pragma unroll
                for (int j = 0; j < 8; ++j) {
                    _Float16 v = h[u][s][j];
                    h[u][s][j] = v > (_Float16)0 ? v : (_Float16)0;
                }

        // ---- mm1: A1 = (relu(h) @ W0a)^T + b0a (k67 hook) ----
        f32x4 A1[2][4];
#pragma unroll
        for (int u = 0; u < 2; ++u)
#pragma unroll
            for (int t = 0; t < 4; ++t) A1[u][t] = (f32x4){0.f, 0.f, 0.f, 0.f};
#pragma unroll
        for (int s = 0; s < 3; ++s)
#pragma unroll
            for (int t = 0; t < 4; ++t) {
                const f16x8 w = WFRAG(s * 4 + t);
                A1[0][t] = __builtin_amdgcn_mfma_f32_16x16x32_f16(w, h[0][s], A1[0][t], 0, 0, 0);
                A1[1][t] = __builtin_amdgcn_mfma_f32_16x16x32_f16(w, h[1][s], A1[1][t], 0, 0, 0);
            }

        // ---- mm2: A2 += (relu(net) @ W1a)^T ----
        f16x8 bf[2][2];
#pragma unroll
        for (int u = 0; u < 2; ++u) pack_relu(A1[u], bf[u]);
#pragma unroll
        for (int s = 0; s < 2; ++s)
#pragma unroll
            for (int t = 0; t < 4; ++t) {
                const f16x8 w = WFRAG(24 + s * 4 + t);
                A2[0][t] = __builtin_amdgcn_mfma_f32_16x16x32_f16(w, bf[0][s], A2[0][t], 0, 0, 0);
                A2[1][t] = __builtin_amdgcn_mfma_f32_16x16x32_f16(w, bf[1][s], A2[1][t], 0, 0, 0);
            }

        // ---- mm4: A1 := b0b (broadcast LDS init) + (relu(h2) @ W0b)^T ----
        //      (A1 slots reused -> only 64 acc regs total live)
#pragma unroll
        for (int u = 0; u < 2; ++u) pack_relu(A2[u], bf[u]);
#pragma unroll
        for (int u = 0; u < 2; ++u)
#pragma unroll
            for (int t = 0; t < 4; ++t) A1[u][t] = *(const f32x4*)&bias3f[16 * t + 4 * q];
#pragma unroll
        for (int s = 0; s < 2; ++s)
#pragma unroll
            for (int t = 0; t < 4; ++t) {
                const f16x8 w = WFRAG(32 + s * 4 + t);
                A1[0][t] = __builtin_amdgcn_mfma_f32_16x16x32_f16(w, bf[0][s], A1[0][t], 0, 0, 0);
                A1[1][t] = __builtin_amdgcn_mfma_f32_16x16x32_f16(w, bf[1][s], A1[1][t], 0, 0, 0);
            }

        // ---- mm5: A2 += (relu(net2) @ W1b)^T  -> h3^T (b1b deferred past max) ----
#pragma unroll
        for (int u = 0; u < 2; ++u) pack_relu(A1[u], bf[u]);
#pragma unroll
        for (int s = 0; s < 2; ++s)
#pragma unroll
            for (int t = 0; t < 4; ++t) {
                const f16x8 w = WFRAG(40 + s * 4 + t);
                A2[0][t] = __builtin_amdgcn_mfma_f32_16x16x32_f16(w, bf[0][s], A2[0][t], 0, 0, 0);
                A2[1][t] = __builtin_amdgcn_mfma_f32_16x16x32_f16(w, bf[1][s], A2[1][t], 0, 0, 0);
            }

        // ---- epilogue: in-register f16 max over dr (lane bits 0..2), no LDS ----
#pragma unroll
        for (int u = 0; u < 2; ++u) {
            union U { f16x8 h; int i[4]; };
            U pa, pb;
#pragma unroll
            for (int e = 0; e < 8; ++e) {
                pa.h[e] = (_Float16)A2[u][(e >> 2)][e & 3];       // feats t=0,1
                pb.h[e] = (_Float16)A2[u][2 + (e >> 2)][e & 3];   // feats t=2,3
            }
#pragma unroll
            for (int st = 0; st < 3; ++st) {
                const int m = 1 << st;                            // xor 1,2,4
                U qa, qb;
#pragma unroll
                for (int d = 0; d < 4; ++d) {
                    qa.i[d] = __shfl_xor(pa.i[d], m, 64);
                    qb.i[d] = __shfl_xor(pb.i[d], m, 64);
                }
#pragma unroll
                for (int e = 0; e < 8; ++e) {
                    pa.h[e] = pa.h[e] > qa.h[e] ? pa.h[e] : qa.h[e];
                    pb.h[e] = pb.h[e] > qb.h[e] ? pb.h[e] : qb.h[e];
                }
            }
            if ((n0 & 7) == 0) {
                const int y = (tA + u) * 2 + (n0 >> 3);
                float* op = out + (long)y * 64;
#pragma unroll
                for (int t = 0; t < 4; ++t) {
                    const f32x4 bb = *(const f32x4*)&bias5f[16 * t + 4 * q];
                    const int e0 = (t & 1) * 4;
                    float4 vst;
                    if (t < 2) vst = {(float)pa.h[e0 + 0] + bb[0], (float)pa.h[e0 + 1] + bb[1],
                                      (float)pa.h[e0 + 2] + bb[2], (float)pa.h[e0 + 3] + bb[3]};
                    else       vst = {(float)pb.h[e0 + 0] + bb[0], (float)pb.h[e0 + 1] + bb[1],
                                      (float)pb.h[e0 + 2] + bb[2], (float)pb.h[e0 + 3] + bb[3]};
                    *(float4*)(op + 16 * t + 4 * q) = vst;
                }
            }
        }

        pnxt = (unsigned)__shfl((int)pnxt, 0);   // late use: atomic latency hidden
        pcur = pnxt;
    }
#undef WFRAG
}

extern "C" void kernel_launch(void* const* d_in, const int* in_sizes, int n_in,
                              void* d_out, int out_size, void* d_ws, size_t ws_size,
                              hipStream_t stream) {
    (void)in_sizes; (void)n_in; (void)ws_size; (void)out_size;
    char* ws = (char*)d_ws;

    prep_x<<<(NX * 16 + 255) / 256, 256, 0, stream>>>((const float*)d_in[0], ws);

    pointnet_fused<<<GRID, BLOCK, 0, stream>>>(
        ws,
        (const float*)d_in[1],   // pos_x
        (const float*)d_in[2],   // pos_y
        (const int*)  d_in[3],   // x_idx
        (const float*)d_in[5],  (const float*)d_in[6],   // W0a, b0a
        (const float*)d_in[7],  (const float*)d_in[8],   // W1a, b1a
        (const float*)d_in[9],                            // Wsa
        (const float*)d_in[10], (const float*)d_in[11],  // W0b, b0b
        (const float*)d_in[12], (const float*)d_in[13],  // W1b, b1b
        (float*)d_out);
}

// Round 7
// 249.112 us; speedup vs baseline: 1.8611x; 1.3170x over previous
//
#include <hip/hip_runtime.h>

// PointNetKnnInterpolator on MI355X (gfx950).
// R17: R12 body VERBATIM (the only proven no-spill fast base: 44.4us fused,
// VGPR 56, WRITE 12.5MB) + exactly ONE change: atomic work-stealing for the
// pair loop (verified correct in R13/R16, never measured without spill).
// Theory: static partition gives 212 of 4096 waves 4 pairs vs 3.05 mean ->
// wall is a 4-pair wave (+31%). Stealing trims wall to ~3.1 pairs.
// Spill gates this round: VGPR 56-60, WRITE ~12.5MB, FETCH ~11.5MB. If
// gates pass and time is neutral, tail theory is falsified on clean data.
// Spill ledger: (512,6)+2-tile=R14, (512,6)+1-tile(3 accs)=R15,
// (512,4)+2-tile+reg-epilogue=R16 all spilled; (512,4)+2-tile+ebuf = clean.
// Falsified: MFMA count (R11), gather prefetch (R11), LDS frag BW (R12),
// pair-ILP (R12), precompute-gather (R13), >4 waves/SIMD w/ this footprint
// (R14/R15), reg-epilogue at 128-reg edge (R16).

typedef _Float16 f16x8 __attribute__((ext_vector_type(8)));
typedef _Float16 f16x4 __attribute__((ext_vector_type(4)));
typedef float    f32x4 __attribute__((ext_vector_type(4)));

constexpr int NX     = 20000;
constexpr int NROWS  = 50000 * 8;    // NY * K
constexpr int NTILES = NROWS / 16;   // 25000
constexpr int NPAIRS = NTILES / 2;   // 12500
constexpr int NFRAG  = 48;           // W0a 12 | Wsa 12 | W1a 8 | W0b 8 | W1b 8
constexpr int BW     = 8;            // waves per block
constexpr int BLOCK  = 64 * BW;      // 512
constexpr int GRID   = 512;          // 2 blocks/CU (LDS 68KB, regs ~120)
constexpr int TS2    = 72;           // epilogue buffer row stride in f16 (+8 pad)

// d_ws layout: x16[NX*64] (f16) | steal counter (unsigned)
#define CTR_BYTE_OFF ((size_t)NX * 64 * 2)

__global__ void prep_x(const float* __restrict__ x, char* __restrict__ ws) {
    _Float16* x16 = (_Float16*)ws;
    const int i = blockIdx.x * blockDim.x + threadIdx.x;   // one float4 each
    if (i < NX * 16) {
        float4 v = ((const float4*)x)[i];
        f16x4 o = {(_Float16)v.x, (_Float16)v.y, (_Float16)v.z, (_Float16)v.w};
        *(f16x4*)(x16 + (size_t)i * 4) = o;
    }
    if (blockIdx.x == 0 && threadIdx.x == 0)
        *(unsigned*)(ws + CTR_BYTE_OFF) = 0u;
}

// relu + repack accumulator (C-layout) into the two K=64 B-fragments.
// frag s element j  <->  acc[t=2s+(j>>2)][r=j&3]   (matches PHI weight layout)
static __device__ __forceinline__ void pack_relu(const f32x4* A, f16x8* bf) {
#pragma unroll
    for (int s = 0; s < 2; ++s) {
        f16x8 r;
#pragma unroll
        for (int e = 0; e < 8; ++e) {
            float v = A[2 * s + (e >> 2)][e & 3];
            r[e] = (_Float16)(v > 0.0f ? v : 0.0f);
        }
        bf[s] = r;
    }
}

__global__ __launch_bounds__(BLOCK, 4)
void pointnet_fused(char* __restrict__ ws,
                    const float* __restrict__ pos_x,
                    const float* __restrict__ pos_y,
                    const int*   __restrict__ x_idx,
                    const float* __restrict__ W0a, const float* __restrict__ b0a,
                    const float* __restrict__ W1a, const float* __restrict__ b1a,
                    const float* __restrict__ Wsa,
                    const float* __restrict__ W0b, const float* __restrict__ b0b,
                    const float* __restrict__ W1b, const float* __restrict__ b1b,
                    float* __restrict__ out)
{
    __shared__ __align__(16) _Float16 bfrag[NFRAG * 64 * 8];   // 48 KiB
    __shared__ __align__(16) _Float16 ebuf[BW][16 * TS2];      // 18 KiB
    __shared__ __align__(16) float    bias3f[64];              // b0b (mm4 acc init)
    __shared__ __align__(16) float    bias5f[64];              // b1b (post-max add)

    const _Float16* x16 = (const _Float16*)ws;
    unsigned* ctr = (unsigned*)(ws + CTR_BYTE_OFF);

    const int tid = threadIdx.x;

    // ---- fill weight fragments (A operands, transposed; PHI-permuted K) ----
    // grp0 W0a(identity,+b0a@k67)  grp1 Wsa(identity,+b1a@k67)
    // grp2 W1a(PHI) grp3 W0b(PHI) grp4 W1b(PHI)
    for (int p = tid; p < NFRAG * 64; p += BLOCK) {
        const int f = p >> 6, l = p & 63;
        const int q = l >> 4, n0 = l & 15;
        int grp, fl;
        if      (f < 12) { grp = 0; fl = f; }
        else if (f < 24) { grp = 1; fl = f - 12; }
        else if (f < 32) { grp = 2; fl = f - 24; }
        else if (f < 40) { grp = 3; fl = f - 32; }
        else             { grp = 4; fl = f - 40; }
        const int s = fl >> 2, t = fl & 3;
        const int col = t * 16 + n0;
        f16x8 v;
#pragma unroll
        for (int j = 0; j < 8; ++j) {
            const int k = 32 * s + 8 * q + j;
            float val = 0.0f;
            if      (grp == 0) val = (k < 67) ? W0a[k * 64 + col] : (k == 67 ? b0a[col] : 0.0f);
            else if (grp == 1) val = (k < 67) ? Wsa[k * 64 + col] : (k == 67 ? b1a[col] : 0.0f);
            else {
                const float* W = (grp == 2) ? W1a : (grp == 3) ? W0b : W1b;
                const int row = 32 * s + 16 * (j >> 2) + 4 * q + (j & 3);  // PHI(k), s<2
                val = W[row * 64 + col];
            }
            v[j] = (_Float16)val;
        }
        *(f16x8*)&bfrag[p * 8] = v;
    }
    if (tid < 64)       bias3f[tid]      = b0b[tid];
    else if (tid < 128) bias5f[tid - 64] = b1b[tid - 64];
    __syncthreads();

    const int lane = tid & 63;
    const int wv   = tid >> 6;
    const int n0   = lane & 15;   // B col = data row (dr) / C-layout col
    const int q    = lane >> 4;

    _Float16* eb = ebuf[wv];

    // epilogue lane roles
    const int ey  = (lane >> 3) & 1;   // y within tile
    const int efg = lane & 7;          // feature group of 8
    const int esb = lane >> 4;         // sub: covers 2 drs

    const unsigned gwave  = blockIdx.x * BW + wv;
    const unsigned nwaves = GRID * BW;   // 4096

#define WFRAG(fid) (*(const f16x8*)&bfrag[(((fid) * 64) + lane) * 8])

    unsigned pcur = gwave;                    // round 1 static (no herd)
    while (pcur < NPAIRS) {
        unsigned pnxt = 0;
        if (lane == 0) pnxt = nwaves + atomicAdd(ctr, 1u);   // steal next pair

        const int tA = (int)pcur * 2;

        // ---- gather both tiles' h (independent -> latencies overlap) ----
        f16x8 h[2][3];
#pragma unroll
        for (int u = 0; u < 2; ++u) {
            const int row = (tA + u) * 16 + n0;
            const int xi  = x_idx[row];
            const _Float16* xp = x16 + (long)xi * 64 + q * 8;
            h[u][0] = *(const f16x8*)(xp);
            h[u][1] = *(const f16x8*)(xp + 32);
            f16x8 z = {};
            h[u][2] = z;
            if (q == 0) {                      // k=64..66 diff, k=67 = 1.0 (bias hook)
                const int yi = row >> 3;
#pragma unroll
                for (int j = 0; j < 3; ++j)
                    h[u][2][j] = (_Float16)(pos_x[xi * 3 + j] - pos_y[yi * 3 + j]);
                h[u][2][3] = (_Float16)1.0f;
            }
        }

        // ---- mm3 on raw h: A2 = (h @ Wsa)^T + b1a (k67 hook) ----
        f32x4 A2[2][4];
#pragma unroll
        for (int u = 0; u < 2; ++u)
#pragma unroll
            for (int t = 0; t < 4; ++t) A2[u][t] = (f32x4){0.f, 0.f, 0.f, 0.f};
#pragma unroll
        for (int s = 0; s < 3; ++s)
#pragma unroll
            for (int t = 0; t < 4; ++t) {
                const f16x8 w = WFRAG(12 + s * 4 + t);     // one LDS read, two MFMAs
                A2[0][t] = __builtin_amdgcn_mfma_f32_16x16x32_f16(w, h[0][s], A2[0][t], 0, 0, 0);
                A2[1][t] = __builtin_amdgcn_mfma_f32_16x16x32_f16(w, h[1][s], A2[1][t], 0, 0, 0);
            }

        // ---- relu h in place (pad 1.0 survives) ----
#pragma unroll
        for (int u = 0; u < 2; ++u)
#pragma unroll
            for (int s = 0; s < 3; ++s)
#pragma unroll
                for (int j = 0; j < 8; ++j) {
                    _Float16 v = h[u][s][j];
                    h[u][s][j] = v > (_Float16)0 ? v : (_Float16)0;
                }

        // ---- mm1: A1 = (relu(h) @ W0a)^T + b0a (k67 hook) ----
        f32x4 A1[2][4];
#pragma unroll
        for (int u = 0; u < 2; ++u)
#pragma unroll
            for (int t = 0; t < 4; ++t) A1[u][t] = (f32x4){0.f, 0.f, 0.f, 0.f};
#pragma unroll
        for (int s = 0; s < 3; ++s)
#pragma unroll
            for (int t = 0; t < 4; ++t) {
                const f16x8 w = WFRAG(s * 4 + t);
                A1[0][t] = __builtin_amdgcn_mfma_f32_16x16x32_f16(w, h[0][s], A1[0][t], 0, 0, 0);
                A1[1][t] = __builtin_amdgcn_mfma_f32_16x16x32_f16(w, h[1][s], A1[1][t], 0, 0, 0);
            }

        // ---- mm2: A2 += (relu(net) @ W1a)^T ----
        f16x8 bf[2][2];
#pragma unroll
        for (int u = 0; u < 2; ++u) pack_relu(A1[u], bf[u]);
#pragma unroll
        for (int s = 0; s < 2; ++s)
#pragma unroll
            for (int t = 0; t < 4; ++t) {
                const f16x8 w = WFRAG(24 + s * 4 + t);
                A2[0][t] = __builtin_amdgcn_mfma_f32_16x16x32_f16(w, bf[0][s], A2[0][t], 0, 0, 0);
                A2[1][t] = __builtin_amdgcn_mfma_f32_16x16x32_f16(w, bf[1][s], A2[1][t], 0, 0, 0);
            }

        // ---- mm4: A1 := b0b (broadcast LDS init) + (relu(h2) @ W0b)^T ----
#pragma unroll
        for (int u = 0; u < 2; ++u) pack_relu(A2[u], bf[u]);
#pragma unroll
        for (int u = 0; u < 2; ++u)
#pragma unroll
            for (int t = 0; t < 4; ++t) A1[u][t] = *(const f32x4*)&bias3f[16 * t + 4 * q];
#pragma unroll
        for (int s = 0; s < 2; ++s)
#pragma unroll
            for (int t = 0; t < 4; ++t) {
                const f16x8 w = WFRAG(32 + s * 4 + t);
                A1[0][t] = __builtin_amdgcn_mfma_f32_16x16x32_f16(w, bf[0][s], A1[0][t], 0, 0, 0);
                A1[1][t] = __builtin_amdgcn_mfma_f32_16x16x32_f16(w, bf[1][s], A1[1][t], 0, 0, 0);
            }

        // ---- mm5: A2 += (relu(net2) @ W1b)^T  -> h3^T (b1b deferred past max) ----
#pragma unroll
        for (int u = 0; u < 2; ++u) pack_relu(A1[u], bf[u]);
#pragma unroll
        for (int s = 0; s < 2; ++s)
#pragma unroll
            for (int t = 0; t < 4; ++t) {
                const f16x8 w = WFRAG(40 + s * 4 + t);
                A2[0][t] = __builtin_amdgcn_mfma_f32_16x16x32_f16(w, bf[0][s], A2[0][t], 0, 0, 0);
                A2[1][t] = __builtin_amdgcn_mfma_f32_16x16x32_f16(w, bf[1][s], A2[1][t], 0, 0, 0);
            }

        // ---- epilogue per tile: h3^T -> ebuf -> shuffle-max -> out ----
#pragma unroll
        for (int u = 0; u < 2; ++u) {
            const int tile = tA + u;
            __threadfence_block();
#pragma unroll
            for (int t = 0; t < 4; ++t) {
                f16x4 w;
#pragma unroll
                for (int r = 0; r < 4; ++r) w[r] = (_Float16)A2[u][t][r];
                *(f16x4*)&eb[n0 * TS2 + t * 16 + q * 4] = w;   // feat = 16t+4q+r
            }
            __threadfence_block();

            // read 2 drs x 8 feats, max-reduce over 8 drs via xor16/xor32 shuffles
            const int dr0 = ey * 8 + esb * 2;
            f16x8 ra = *(const f16x8*)&eb[dr0 * TS2 + efg * 8];
            f16x8 rb = *(const f16x8*)&eb[(dr0 + 1) * TS2 + efg * 8];
#pragma unroll
            for (int e = 0; e < 8; ++e) ra[e] = ra[e] > rb[e] ? ra[e] : rb[e];
#pragma unroll
            for (int st = 0; st < 2; ++st) {
                union { f16x8 h; int i[4]; } uu, v2;
                uu.h = ra;
#pragma unroll
                for (int d = 0; d < 4; ++d) v2.i[d] = __shfl_xor(uu.i[d], st == 0 ? 16 : 32, 64);
#pragma unroll
                for (int e = 0; e < 8; ++e) ra[e] = ra[e] > v2.h[e] ? ra[e] : v2.h[e];
            }
            if (esb == 0) {
                const f32x4 bb0 = *(const f32x4*)&bias5f[efg * 8];
                const f32x4 bb1 = *(const f32x4*)&bias5f[efg * 8 + 4];
                float4 f0 = {(float)ra[0] + bb0[0], (float)ra[1] + bb0[1],
                             (float)ra[2] + bb0[2], (float)ra[3] + bb0[3]};
                float4 f1 = {(float)ra[4] + bb1[0], (float)ra[5] + bb1[1],
                             (float)ra[6] + bb1[2], (float)ra[7] + bb1[3]};
                float* op = out + (long)(tile * 2 + ey) * 64 + efg * 8;
                *(float4*)op = f0;
                *(float4*)(op + 4) = f1;
            }
        }

        pnxt = (unsigned)__shfl((int)pnxt, 0);   // late use: atomic latency hidden
        pcur = pnxt;
    }
#undef WFRAG
}

extern "C" void kernel_launch(void* const* d_in, const int* in_sizes, int n_in,
                              void* d_out, int out_size, void* d_ws, size_t ws_size,
                              hipStream_t stream) {
    (void)in_sizes; (void)n_in; (void)ws_size; (void)out_size;
    char* ws = (char*)d_ws;

    prep_x<<<(NX * 16 + 255) / 256, 256, 0, stream>>>((const float*)d_in[0], ws);

    pointnet_fused<<<GRID, BLOCK, 0, stream>>>(
        ws,
        (const float*)d_in[1],   // pos_x
        (const float*)d_in[2],   // pos_y
        (const int*)  d_in[3],   // x_idx
        (const float*)d_in[5],  (const float*)d_in[6],   // W0a, b0a
        (const float*)d_in[7],  (const float*)d_in[8],   // W1a, b1a
        (const float*)d_in[9],                            // Wsa
        (const float*)d_in[10], (const float*)d_in[11],  // W0b, b0b
        (const float*)d_in[12], (const float*)d_in[13],  // W1b, b1b
        (float*)d_out);
}